// Round 2
// baseline (3455.433 us; speedup 1.0000x reference)
//
#include <hip/hip_runtime.h>
#include <math.h>

#define TLEN 2048

// Block = one (batch*head, 64-row t-tile). 256 threads = 16x16 grid, 4x4 micro-tiles.
// Flash-style online softmax over s-tiles of 64. fp32 everywhere (round-0 correctness
// baseline; bf16 MFMA conversion planned once absmax headroom is known).
//
// LDS budget (must stay < 64 KiB/block):
//   Qs[64][64]  (c-major, t-minor)        16384 B
//   KS[64][68]  K-tile, then aliased as P 17408 B   (P stored [s][t], pad 68 for 16B-aligned float4 reads)
//   Vs[64][68]  V-tile transposed [s][c]  17408 B
//   m/l/corr stats                          768 B
//   total ~51.9 KiB -> 2 blocks/CU (104 KiB of 160 KiB)
__global__ __launch_bounds__(256, 2)
void wqkv_attn_fp32(const float* __restrict__ qkv,
                    const float* __restrict__ wm,
                    float* __restrict__ out) {
  const int bh = blockIdx.x & 15;          // head index fastest -> 2 heads/XCD in L2
  const int t0 = (blockIdx.x >> 4) << 6;   // t-tile origin
  const int b  = bh >> 3;
  const int h  = bh & 7;
  const int tid = threadIdx.x;
  const int tx = tid & 15;                 // QK: s-group / PV: t-group
  const int ty = tid >> 4;                 // QK: t-group / PV: c-group

  __shared__ float Qs[64][64];             // [c][t]
  __shared__ float KS[64][68];             // K-tile as [c][s] (stride 68), then P as [s][t]
  __shared__ float Vs[64][68];             // [s][c] (transposed)
  __shared__ float m_l[64], l_l[64], c_l[64];

  const float* qb   = qkv + ((size_t)b * 1536 + (size_t)h * 64) * TLEN;
  const float* kb   = qb + (size_t)512  * TLEN;
  const float* vb   = qb + (size_t)1024 * TLEN;
  const float* wrow = wm + ((size_t)bh * TLEN + (size_t)t0) * TLEN;

  // ---- load Q tile: Qs[c][t-local] ----
  #pragma unroll
  for (int j = 0; j < 4; ++j) {
    int flat = tid + j * 256;              // float4 units, 1024 total
    int c = flat >> 4, u = flat & 15;
    *(float4*)&Qs[c][u * 4] = *(const float4*)(qb + (size_t)c * TLEN + t0 + u * 4);
  }
  if (tid < 64) { m_l[tid] = -3.0e38f; l_l[tid] = 0.0f; }

  float acc[4][4] = {{0.f, 0.f, 0.f, 0.f}};   // [c-sub][t-sub]

  __syncthreads();

  for (int st = 0; st < TLEN / 64; ++st) {
    const int s0 = st * 64;

    // ---- stage K (linear) and V (transposed) tiles ----
    #pragma unroll
    for (int j = 0; j < 4; ++j) {
      int flat = tid + j * 256;
      int c = flat >> 4, u = flat & 15;
      *(float4*)&KS[c][u * 4] = *(const float4*)(kb + (size_t)c * TLEN + s0 + u * 4);
      float4 v4 = *(const float4*)(vb + (size_t)c * TLEN + s0 + u * 4);
      Vs[u * 4 + 0][c] = v4.x;
      Vs[u * 4 + 1][c] = v4.y;
      Vs[u * 4 + 2][c] = v4.z;
      Vs[u * 4 + 3][c] = v4.w;
    }
    __syncthreads();

    // ---- S[t][s] = sum_c Q[c][t] * K[c][s] ----
    float S[4][4] = {{0.f, 0.f, 0.f, 0.f}};
    #pragma unroll
    for (int c = 0; c < 64; ++c) {
      const float4 q4 = *(const float4*)&Qs[c][ty * 4];
      const float4 k4 = *(const float4*)&KS[c][tx * 4];
      const float qa[4] = {q4.x, q4.y, q4.z, q4.w};
      const float ka[4] = {k4.x, k4.y, k4.z, k4.w};
      #pragma unroll
      for (int i = 0; i < 4; ++i)
        #pragma unroll
        for (int j = 0; j < 4; ++j)
          S[i][j] = fmaf(qa[i], ka[j], S[i][j]);
    }
    __syncthreads();   // all K reads done before P aliases KS

    // ---- weight-mult + online softmax; write P (aliased over KS) as [s][t] ----
    #pragma unroll
    for (int i = 0; i < 4; ++i) {
      const int r = ty * 4 + i;            // local t row
      const float4 w4 = *(const float4*)(wrow + (size_t)r * TLEN + s0 + tx * 4);
      float sv[4];
      sv[0] = S[i][0] * 0.125f * w4.x;     // scale^2 = 1/sqrt(64) = 1/8
      sv[1] = S[i][1] * 0.125f * w4.y;
      sv[2] = S[i][2] * 0.125f * w4.z;
      sv[3] = S[i][3] * 0.125f * w4.w;
      float mx = fmaxf(fmaxf(sv[0], sv[1]), fmaxf(sv[2], sv[3]));
      #pragma unroll
      for (int off = 1; off < 16; off <<= 1)
        mx = fmaxf(mx, __shfl_xor(mx, off));
      const float mo = m_l[r];             // read-before-write within same 16-lane group
      const float mn = fmaxf(mo, mx);
      const float co = __expf(mo - mn);
      float sum = 0.f;
      #pragma unroll
      for (int j = 0; j < 4; ++j) { sv[j] = __expf(sv[j] - mn); sum += sv[j]; }
      #pragma unroll
      for (int off = 1; off < 16; off <<= 1)
        sum += __shfl_xor(sum, off);
      if (tx == 0) { m_l[r] = mn; c_l[r] = co; l_l[r] = l_l[r] * co + sum; }
      #pragma unroll
      for (int j = 0; j < 4; ++j)
        KS[tx * 4 + j][r] = sv[j];         // P[s][t]
    }
    __syncthreads();

    // ---- PV: O[c][t] = corr*O + sum_s P[t][s] * V[c][s] ----
    float cr[4];
    #pragma unroll
    for (int j = 0; j < 4; ++j) cr[j] = c_l[tx * 4 + j];
    #pragma unroll
    for (int i = 0; i < 4; ++i)
      #pragma unroll
      for (int j = 0; j < 4; ++j)
        acc[i][j] *= cr[j];
    #pragma unroll
    for (int s = 0; s < 64; ++s) {
      const float4 v4 = *(const float4*)&Vs[s][ty * 4];
      const float4 p4 = *(const float4*)&KS[s][tx * 4];
      const float va[4] = {v4.x, v4.y, v4.z, v4.w};
      const float pa[4] = {p4.x, p4.y, p4.z, p4.w};
      #pragma unroll
      for (int i = 0; i < 4; ++i)
        #pragma unroll
        for (int j = 0; j < 4; ++j)
          acc[i][j] = fmaf(va[i], pa[j], acc[i][j]);
    }
    __syncthreads();   // protect KS/Vs/stats before next tile
  }

  // ---- epilogue: divide by l, write out[b][h*64+c][t] ----
  float linv[4];
  #pragma unroll
  for (int j = 0; j < 4; ++j) linv[j] = 1.0f / l_l[tx * 4 + j];
  #pragma unroll
  for (int i = 0; i < 4; ++i) {
    float4 o;
    o.x = acc[i][0] * linv[0];
    o.y = acc[i][1] * linv[1];
    o.z = acc[i][2] * linv[2];
    o.w = acc[i][3] * linv[3];
    *(float4*)(out + ((size_t)b * 512 + (size_t)h * 64 + ty * 4 + i) * TLEN + t0 + tx * 4) = o;
  }
}

extern "C" void kernel_launch(void* const* d_in, const int* in_sizes, int n_in,
                              void* d_out, int out_size, void* d_ws, size_t ws_size,
                              hipStream_t stream) {
  const float* qkv = (const float*)d_in[0];     // (2, 1536, 2048) fp32
  const float* wm  = (const float*)d_in[1];     // (16, 2048, 2048) fp32
  float* out = (float*)d_out;                   // (2, 512, 2048) fp32
  dim3 grid(512);
  dim3 block(256);
  hipLaunchKernelGGL(wqkv_attn_fp32, grid, block, 0, stream, qkv, wm, out);
}

// Round 3
// 636.304 us; speedup vs baseline: 5.4305x; 5.4305x over previous
//
#include <hip/hip_runtime.h>
#include <math.h>

#define TLEN 2048

// Block = one (batch*head, 64-row t-tile). 256 threads = 16x16 grid, 4x4 micro-tiles.
// Flash-style online softmax over s-tiles of 64. fp32 everywhere.
//
// R2 lesson: full `#pragma unroll` on the 64-deep c/s loops made the scheduler
// hoist ds_reads past the 128-VGPR budget -> in-loop scratch spills ->
// 4.77 GB of spill WRITES per dispatch (vs 17 MB real output), 3.3 ms.
// Fix: unroll 8 so each scheduling window is 16 ds_reads + 128 FMAs.
//
// LDS budget:
//   Qs[64][64]  (c-major, t-minor)        16384 B
//   KS[64][68]  K-tile, then aliased as P 17408 B
//   Vs[64][68]  V-tile transposed [s][c]  17408 B
//   m/l/corr stats                          768 B
//   total ~51.9 KiB -> 2 blocks/CU
__global__ __launch_bounds__(256, 2)
void wqkv_attn_fp32(const float* __restrict__ qkv,
                    const float* __restrict__ wm,
                    float* __restrict__ out) {
  const int bh = blockIdx.x & 15;          // head index fastest
  const int t0 = (blockIdx.x >> 4) << 6;   // t-tile origin
  const int b  = bh >> 3;
  const int h  = bh & 7;
  const int tid = threadIdx.x;
  const int tx = tid & 15;                 // QK: s-group / PV: t-group
  const int ty = tid >> 4;                 // QK: t-group / PV: c-group

  __shared__ float Qs[64][64];             // [c][t]
  __shared__ float KS[64][68];             // K-tile as [c][s], then P as [s][t]
  __shared__ float Vs[64][68];             // [s][c] (transposed)
  __shared__ float m_l[64], l_l[64], c_l[64];

  const float* qb   = qkv + ((size_t)b * 1536 + (size_t)h * 64) * TLEN;
  const float* kb   = qb + (size_t)512  * TLEN;
  const float* vb   = qb + (size_t)1024 * TLEN;
  const float* wrow = wm + ((size_t)bh * TLEN + (size_t)t0) * TLEN;

  // ---- load Q tile: Qs[c][t-local] ----
  #pragma unroll
  for (int j = 0; j < 4; ++j) {
    int flat = tid + j * 256;              // float4 units, 1024 total
    int c = flat >> 4, u = flat & 15;
    *(float4*)&Qs[c][u * 4] = *(const float4*)(qb + (size_t)c * TLEN + t0 + u * 4);
  }
  if (tid < 64) { m_l[tid] = -3.0e38f; l_l[tid] = 0.0f; }

  float acc[4][4] = {{0.f, 0.f, 0.f, 0.f}};   // [c-sub][t-sub]

  __syncthreads();

  for (int st = 0; st < TLEN / 64; ++st) {
    const int s0 = st * 64;

    // ---- stage K (linear) and V (transposed) tiles ----
    #pragma unroll
    for (int j = 0; j < 4; ++j) {
      int flat = tid + j * 256;
      int c = flat >> 4, u = flat & 15;
      *(float4*)&KS[c][u * 4] = *(const float4*)(kb + (size_t)c * TLEN + s0 + u * 4);
      float4 v4 = *(const float4*)(vb + (size_t)c * TLEN + s0 + u * 4);
      Vs[u * 4 + 0][c] = v4.x;
      Vs[u * 4 + 1][c] = v4.y;
      Vs[u * 4 + 2][c] = v4.z;
      Vs[u * 4 + 3][c] = v4.w;
    }
    __syncthreads();

    // ---- S[t][s] = sum_c Q[c][t] * K[c][s] ----
    float S[4][4] = {{0.f, 0.f, 0.f, 0.f}};
    #pragma unroll 8
    for (int c = 0; c < 64; ++c) {
      const float4 q4 = *(const float4*)&Qs[c][ty * 4];
      const float4 k4 = *(const float4*)&KS[c][tx * 4];
      const float qa[4] = {q4.x, q4.y, q4.z, q4.w};
      const float ka[4] = {k4.x, k4.y, k4.z, k4.w};
      #pragma unroll
      for (int i = 0; i < 4; ++i)
        #pragma unroll
        for (int j = 0; j < 4; ++j)
          S[i][j] = fmaf(qa[i], ka[j], S[i][j]);
    }
    __syncthreads();   // all K reads done before P aliases KS

    // ---- weight-mult + online softmax; write P (aliased over KS) as [s][t] ----
    #pragma unroll
    for (int i = 0; i < 4; ++i) {
      const int r = ty * 4 + i;            // local t row
      const float4 w4 = *(const float4*)(wrow + (size_t)r * TLEN + s0 + tx * 4);
      float sv[4];
      sv[0] = S[i][0] * 0.125f * w4.x;     // scale^2 = 1/sqrt(64) = 1/8
      sv[1] = S[i][1] * 0.125f * w4.y;
      sv[2] = S[i][2] * 0.125f * w4.z;
      sv[3] = S[i][3] * 0.125f * w4.w;
      float mx = fmaxf(fmaxf(sv[0], sv[1]), fmaxf(sv[2], sv[3]));
      #pragma unroll
      for (int off = 1; off < 16; off <<= 1)
        mx = fmaxf(mx, __shfl_xor(mx, off));
      const float mo = m_l[r];
      const float mn = fmaxf(mo, mx);
      const float co = __expf(mo - mn);
      float sum = 0.f;
      #pragma unroll
      for (int j = 0; j < 4; ++j) { sv[j] = __expf(sv[j] - mn); sum += sv[j]; }
      #pragma unroll
      for (int off = 1; off < 16; off <<= 1)
        sum += __shfl_xor(sum, off);
      if (tx == 0) { m_l[r] = mn; c_l[r] = co; l_l[r] = l_l[r] * co + sum; }
      #pragma unroll
      for (int j = 0; j < 4; ++j)
        KS[tx * 4 + j][r] = sv[j];         // P[s][t]
    }
    __syncthreads();

    // ---- PV: O[c][t] = corr*O + sum_s P[t][s] * V[c][s] ----
    float cr[4];
    #pragma unroll
    for (int j = 0; j < 4; ++j) cr[j] = c_l[tx * 4 + j];
    #pragma unroll
    for (int i = 0; i < 4; ++i)
      #pragma unroll
      for (int j = 0; j < 4; ++j)
        acc[i][j] *= cr[j];
    #pragma unroll 8
    for (int s = 0; s < 64; ++s) {
      const float4 v4 = *(const float4*)&Vs[s][ty * 4];
      const float4 p4 = *(const float4*)&KS[s][tx * 4];
      const float va[4] = {v4.x, v4.y, v4.z, v4.w};
      const float pa[4] = {p4.x, p4.y, p4.z, p4.w};
      #pragma unroll
      for (int i = 0; i < 4; ++i)
        #pragma unroll
        for (int j = 0; j < 4; ++j)
          acc[i][j] = fmaf(va[i], pa[j], acc[i][j]);
    }
    __syncthreads();   // protect KS/Vs/stats before next tile
  }

  // ---- epilogue: divide by l, write out[b][h*64+c][t] ----
  float linv[4];
  #pragma unroll
  for (int j = 0; j < 4; ++j) linv[j] = 1.0f / l_l[tx * 4 + j];
  #pragma unroll
  for (int i = 0; i < 4; ++i) {
    float4 o;
    o.x = acc[i][0] * linv[0];
    o.y = acc[i][1] * linv[1];
    o.z = acc[i][2] * linv[2];
    o.w = acc[i][3] * linv[3];
    *(float4*)(out + ((size_t)b * 512 + (size_t)h * 64 + ty * 4 + i) * TLEN + t0 + tx * 4) = o;
  }
}

extern "C" void kernel_launch(void* const* d_in, const int* in_sizes, int n_in,
                              void* d_out, int out_size, void* d_ws, size_t ws_size,
                              hipStream_t stream) {
  const float* qkv = (const float*)d_in[0];     // (2, 1536, 2048) fp32
  const float* wm  = (const float*)d_in[1];     // (16, 2048, 2048) fp32
  float* out = (float*)d_out;                   // (2, 512, 2048) fp32
  dim3 grid(512);
  dim3 block(256);
  hipLaunchKernelGGL(wqkv_attn_fp32, grid, block, 0, stream, qkv, wm, out);
}

// Round 7
// 397.075 us; speedup vs baseline: 8.7022x; 1.6025x over previous
//
#include <hip/hip_runtime.h>
#include <math.h>

#define TLEN 2048

typedef __attribute__((ext_vector_type(8))) short bf16x8;
typedef __attribute__((ext_vector_type(4))) float f32x4;

__device__ __forceinline__ unsigned fbits(float x){ union{float f; unsigned u;} a; a.f=x; return a.u; }
__device__ __forceinline__ float bitsf(unsigned u){ union{unsigned u; float f;} a; a.u=u; return a.f; }
// fp32 -> bf16 round-to-nearest-even
__device__ __forceinline__ unsigned short f2b(float x){
  unsigned u = fbits(x);
  return (unsigned short)((u + 0x7fffu + ((u>>16)&1u)) >> 16);
}

// Swapped-layout MFMA flash attention, one (bh, 64-t-tile) per block, 4 waves.
//  QK^T: S^T[s][t] = mfma(A=K^T frag, B=Q frag)  -> softmax is lane-local (lane owns column t)
//  bf16x2 for Q,K (hi/lo; drop lo*lo), hi/lo for V, plain bf16 for P.
//  K transpose-staged [s][c] with XOR c-block swizzle (write & read both apply it).
//  P rows are wave-private -> no barrier between P write and PV read.
//  2 barriers per s-tile. LDS 62464 B -> 2 blocks/CU.
__global__ __launch_bounds__(256, 2)
void wqkv_attn_mfma(const float* __restrict__ qkv,
                    const float* __restrict__ wm,
                    float* __restrict__ out) {
  const int bh = blockIdx.x & 15;          // head fastest: a head's 32 t-blocks share an XCD L2
  const int t0 = (blockIdx.x >> 4) << 6;
  const int b  = bh >> 3;
  const int h  = bh & 7;
  const int tid  = threadIdx.x;
  const int w    = tid >> 6;               // wave 0..3, owns t-strip [16w,16w+16)
  const int lane = tid & 63;
  const int lt   = lane & 15;
  const int q4   = lane >> 4;

  __shared__ __align__(16) unsigned short Qhi[64][64], Qlo[64][64]; // [t][c]
  __shared__ __align__(16) unsigned short Khi[64][72], Klo[64][72]; // [s][c] swizzled
  __shared__ __align__(16) unsigned short Vhi[64][72], Vlo[64][72]; // [c][s]
  __shared__ __align__(16) unsigned short Pl [64][72];              // [t][s]

  const float* qb   = qkv + ((size_t)b*1536 + (size_t)h*64) * TLEN;
  const float* kb   = qb + (size_t)512  * TLEN;
  const float* vb   = qb + (size_t)1024 * TLEN;
  const float* wmat = wm + (size_t)bh * TLEN * TLEN;

  // ---- Q prologue: global [c][t] fp32 -> LDS [t][c] hi/lo bf16 ----
  #pragma unroll
  for (int j = 0; j < 4; ++j) {
    int flat = tid + j*256;
    int c = flat >> 4, u = flat & 15;
    float4 v = *(const float4*)(qb + (size_t)c*TLEN + t0 + 4*u);
    float xs[4] = {v.x, v.y, v.z, v.w};
    #pragma unroll
    for (int i = 0; i < 4; ++i) {
      unsigned hb = fbits(xs[i]) & 0xffff0000u;      // truncation hi (lo catches the rest)
      Qhi[4*u+i][c] = (unsigned short)(hb >> 16);
      Qlo[4*u+i][c] = f2b(xs[i] - bitsf(hb));
    }
  }
  __syncthreads();

  // Hoist Q B-frags for this wave's t-strip: B[k=c][n=t], lane: t=16w+lt, c=32kc+8q4+j
  bf16x8 qfh[2], qfl[2];
  #pragma unroll
  for (int kc = 0; kc < 2; ++kc) {
    qfh[kc] = *(const bf16x8*)&Qhi[16*w + lt][32*kc + 8*q4];
    qfl[kc] = *(const bf16x8*)&Qlo[16*w + lt][32*kc + 8*q4];
  }

  f32x4 accO[4];
  #pragma unroll
  for (int i = 0; i < 4; ++i) accO[i] = (f32x4){0.f,0.f,0.f,0.f};
  float m_run = -1e30f, l_run = 0.0f;

  for (int st = 0; st < 32; ++st) {
    const int s0 = st * 64;

    __syncthreads();   // all waves' prior-iter K/V reads done before re-staging

    // ---- W prefetch (consumed in softmax; overlaps staging + QK) ----
    float4 wv[4];
    #pragma unroll
    for (int fm = 0; fm < 4; ++fm)
      wv[fm] = *(const float4*)(wmat + (size_t)(t0 + 16*w + lt)*TLEN + s0 + 16*fm + 4*q4);

    // ---- stage K (transposed [s][c], swizzled) and V ([c][s]) hi/lo ----
    #pragma unroll
    for (int j = 0; j < 4; ++j) {
      int flat = tid + j*256;
      int c = flat >> 4, u = flat & 15;            // K/V elem (c, s=4u..4u+3)
      float4 kv = *(const float4*)(kb + (size_t)c*TLEN + s0 + 4*u);
      int pc = c ^ (8*(u & 7));                    // swizzle: c-block ^= (s>>2)&7 (s>>2 == u)
      float ks[4] = {kv.x,kv.y,kv.z,kv.w};
      #pragma unroll
      for (int i = 0; i < 4; ++i) {
        unsigned hb = fbits(ks[i]) & 0xffff0000u;
        Khi[4*u+i][pc] = (unsigned short)(hb >> 16);
        Klo[4*u+i][pc] = f2b(ks[i] - bitsf(hb));
      }
      float4 vv = *(const float4*)(vb + (size_t)c*TLEN + s0 + 4*u);
      unsigned xh = (fbits(vv.x)>>16) | (fbits(vv.y) & 0xffff0000u);
      unsigned yh = (fbits(vv.z)>>16) | (fbits(vv.w) & 0xffff0000u);
      unsigned xl = (unsigned)f2b(vv.x - bitsf(fbits(vv.x)&0xffff0000u))
                  | ((unsigned)f2b(vv.y - bitsf(fbits(vv.y)&0xffff0000u)) << 16);
      unsigned yl = (unsigned)f2b(vv.z - bitsf(fbits(vv.z)&0xffff0000u))
                  | ((unsigned)f2b(vv.w - bitsf(fbits(vv.w)&0xffff0000u)) << 16);
      *(uint2*)&Vhi[c][4*u] = make_uint2(xh, yh);
      *(uint2*)&Vlo[c][4*u] = make_uint2(xl, yl);
    }
    __syncthreads();

    // ---- QK^T: acc[fm] = S^T rows s=16fm+4q4+reg, col t=16w+lt ----
    f32x4 acc[4];
    #pragma unroll
    for (int fm = 0; fm < 4; ++fm) {
      f32x4 a = (f32x4){0.f,0.f,0.f,0.f};
      const int srow = 16*fm + lt;
      const int f = (4*fm + (lt >> 2)) & 7;        // (s>>2)&7 for s = 16fm+lt
      #pragma unroll
      for (int kc = 0; kc < 2; ++kc) {
        const int blk = (4*kc + q4) ^ f;           // swizzled c-block
        bf16x8 kh = *(const bf16x8*)&Khi[srow][8*blk];
        bf16x8 kl = *(const bf16x8*)&Klo[srow][8*blk];
        a = __builtin_amdgcn_mfma_f32_16x16x32_bf16(kh, qfh[kc], a, 0,0,0);
        a = __builtin_amdgcn_mfma_f32_16x16x32_bf16(kh, qfl[kc], a, 0,0,0);
        a = __builtin_amdgcn_mfma_f32_16x16x32_bf16(kl, qfh[kc], a, 0,0,0);
      }
      acc[fm] = a;
    }

    // ---- weight-mult + online softmax (lane-local column t) ----
    float sv[4][4];
    float mx = -1e30f;
    #pragma unroll
    for (int fm = 0; fm < 4; ++fm) {
      float wvf[4] = {wv[fm].x, wv[fm].y, wv[fm].z, wv[fm].w};
      #pragma unroll
      for (int r = 0; r < 4; ++r) {
        float x = acc[fm][r] * 0.125f * wvf[r];    // scale^2 = 1/8, then Weight_Mat
        sv[fm][r] = x;
        mx = fmaxf(mx, x);
      }
    }
    mx = fmaxf(mx, __shfl_xor(mx, 16));
    mx = fmaxf(mx, __shfl_xor(mx, 32));
    const float mn   = fmaxf(m_run, mx);
    const float corr = __expf(m_run - mn);
    m_run = mn;
    float sum = 0.f;
    unsigned short pb[4][4];
    #pragma unroll
    for (int fm = 0; fm < 4; ++fm)
      #pragma unroll
      for (int r = 0; r < 4; ++r) {
        float p = __expf(sv[fm][r] - mn);
        sum += p;
        pb[fm][r] = f2b(p);
      }
    sum += __shfl_xor(sum, 16);
    sum += __shfl_xor(sum, 32);
    l_run = l_run * corr + sum;
    #pragma unroll
    for (int fm = 0; fm < 4; ++fm)
      #pragma unroll
      for (int r = 0; r < 4; ++r)
        accO[fm][r] *= corr;

    // ---- write P rows (wave-private: rows 16w+lt) ----
    #pragma unroll
    for (int fm = 0; fm < 4; ++fm) {
      unsigned p01 = (unsigned)pb[fm][0] | ((unsigned)pb[fm][1] << 16);
      unsigned p23 = (unsigned)pb[fm][2] | ((unsigned)pb[fm][3] << 16);
      *(uint2*)&Pl[16*w + lt][16*fm + 4*q4] = make_uint2(p01, p23);
    }

    // ---- PV: accO[fm] += mfma(A=V rows c=16fm+lt, B=P) ----
    #pragma unroll
    for (int kc = 0; kc < 2; ++kc) {
      bf16x8 pf = *(const bf16x8*)&Pl[16*w + lt][32*kc + 8*q4];
      #pragma unroll
      for (int fm = 0; fm < 4; ++fm) {
        bf16x8 vh = *(const bf16x8*)&Vhi[16*fm + lt][32*kc + 8*q4];
        bf16x8 vl = *(const bf16x8*)&Vlo[16*fm + lt][32*kc + 8*q4];
        accO[fm] = __builtin_amdgcn_mfma_f32_16x16x32_bf16(vh, pf, accO[fm], 0,0,0);
        accO[fm] = __builtin_amdgcn_mfma_f32_16x16x32_bf16(vl, pf, accO[fm], 0,0,0);
      }
    }
  }

  // ---- epilogue: normalize, store out[b][h*64+c][t0+16w+lt] ----
  const float inv = 1.0f / l_run;
  #pragma unroll
  for (int fm = 0; fm < 4; ++fm)
    #pragma unroll
    for (int r = 0; r < 4; ++r) {
      int c = 16*fm + 4*q4 + r;
      out[((size_t)b*512 + (size_t)h*64 + c)*TLEN + t0 + 16*w + lt] = accO[fm][r] * inv;
    }
}

extern "C" void kernel_launch(void* const* d_in, const int* in_sizes, int n_in,
                              void* d_out, int out_size, void* d_ws, size_t ws_size,
                              hipStream_t stream) {
  const float* qkv = (const float*)d_in[0];     // (2, 1536, 2048) fp32
  const float* wm  = (const float*)d_in[1];     // (16, 2048, 2048) fp32
  float* out = (float*)d_out;                   // (2, 512, 2048) fp32
  dim3 grid(512);
  dim3 block(256);
  hipLaunchKernelGGL(wqkv_attn_mfma, grid, block, 0, stream, qkv, wm, out);
}